// Round 7
// baseline (167.241 us; speedup 1.0000x reference)
//
#include <hip/hip_runtime.h>
#include <math.h>

typedef float f32x4_t __attribute__((ext_vector_type(4)));
typedef short bf16x8_t __attribute__((ext_vector_type(8)));

#define B_   8
#define C_   512
#define T_   1024
#define NH_  8
#define CH_  64
#define EPSF 1e-5f

#define MFMA16(a, b, c) __builtin_amdgcn_mfma_f32_16x16x32_bf16((a), (b), (c), 0, 0, 0)

__device__ __forceinline__ unsigned short f2bf(float f) {
  union { float f; unsigned u; } v; v.f = f;
  unsigned r = v.u + 0x7FFFu + ((v.u >> 16) & 1u);
  return (unsigned short)(r >> 16);
}

// async 16B/lane direct global->LDS (global_load_lds_dwordx4).
// lds dest must be wave-uniform base; HW adds lane*16.
typedef const unsigned int u32_g __attribute__((address_space(1)));
typedef unsigned int u32_l __attribute__((address_space(3)));
__device__ __forceinline__ void gld16(const unsigned short* g, unsigned short* l) {
  __builtin_amdgcn_global_load_lds((u32_g*)g, (u32_l*)l, 16, 0, 0);
}
// stage one 128x32 bf16 tile (8KB, globally contiguous) with 256 threads
__device__ __forceinline__ void load_tile(const unsigned short* g,
                                          unsigned short* l, int tid) {
  int wb = (tid >> 6) * 512;          // wave-uniform lds chunk (1KB/wave)
  gld16(g + tid * 8,        l + wb);
  gld16(g + 2048 + tid * 8, l + 2048 + wb);
}

// ---------------------------------------------------------------------------
// Fused prep: blocks 0..255 GroupNorm -> xnP[b][kp][t][32] bf16 panels;
// blocks 256.. weights fp32->bf16 panels qwP[kp][o][32], pwP[kp][o][32].
// ---------------------------------------------------------------------------
__global__ __launch_bounds__(256) void prep_gn_kernel(
    const float* __restrict__ x, const float* __restrict__ w,
    const float* __restrict__ bvec, unsigned short* __restrict__ xnP,
    const float* __restrict__ qw_f, const float* __restrict__ pw_f,
    unsigned short* __restrict__ qwP, unsigned short* __restrict__ pwP)
{
  int tid = threadIdx.x;
  if (blockIdx.x >= 256) {
    int idx = (blockIdx.x - 256) * 256 + tid;    // float4 granularity
    const int N1 = 1536 * 512 / 4;
    const int N2 = 512 * 512 / 4;
    if (idx < N1) {
      float4 v = ((const float4*)qw_f)[idx];
      int o = idx >> 7, cq = (idx & 127) * 4;
      uint2 ov;
      ov.x = (unsigned)f2bf(v.x) | ((unsigned)f2bf(v.y) << 16);
      ov.y = (unsigned)f2bf(v.z) | ((unsigned)f2bf(v.w) << 16);
      *(uint2*)&qwP[((size_t)(cq >> 5) * 1536 + o) * 32 + (cq & 31)] = ov;
    } else if (idx < N1 + N2) {
      int j = idx - N1;
      float4 v = ((const float4*)pw_f)[j];
      int o = j >> 7, cq = (j & 127) * 4;
      uint2 ov;
      ov.x = (unsigned)f2bf(v.x) | ((unsigned)f2bf(v.y) << 16);
      ov.y = (unsigned)f2bf(v.z) | ((unsigned)f2bf(v.w) << 16);
      *(uint2*)&pwP[((size_t)(cq >> 5) * 512 + o) * 32 + (cq & 31)] = ov;
    }
    return;
  }

  int blk = blockIdx.x;            // b*32 + g
  int b = blk >> 5, g = blk & 31;
  const float* xp = x + ((size_t)(b * C_ + g * 16)) * T_;
  const int N = 16 * T_;           // 16384

  float s = 0.f, s2 = 0.f;
  for (int i = tid * 4; i < N; i += 256 * 4) {
    float4 v = *(const float4*)(xp + i);
    s  += v.x + v.y + v.z + v.w;
    s2 += v.x * v.x + v.y * v.y + v.z * v.z + v.w * v.w;
  }
  for (int off = 32; off; off >>= 1) {
    s  += __shfl_down(s,  off, 64);
    s2 += __shfl_down(s2, off, 64);
  }
  __shared__ float rs_[4], r2_[4];
  __shared__ float mu_s, rsig_s;
  int wid = tid >> 6, lane = tid & 63;
  if (lane == 0) { rs_[wid] = s; r2_[wid] = s2; }
  __syncthreads();
  if (tid == 0) {
    float ts = rs_[0] + rs_[1] + rs_[2] + rs_[3];
    float t2 = r2_[0] + r2_[1] + r2_[2] + r2_[3];
    float mu = ts / (float)N;
    float var = t2 / (float)N - mu * mu;
    mu_s = mu;
    rsig_s = rsqrtf(var + EPSF);
  }
  __syncthreads();
  float mu = mu_s, rs = rsig_s;

  float wl[16], bl[16];
  for (int c = 0; c < 16; ++c) { wl[c] = w[g * 16 + c]; bl[c] = bvec[g * 16 + c]; }

  // group g -> panel kp = g>>1, half offset (g&1)*16
  unsigned short* dbase = xnP + ((size_t)(b * 16 + (g >> 1)) * T_) * 32 + (g & 1) * 16;
  for (int t = tid; t < T_; t += 256) {
    unsigned short buf[16] __attribute__((aligned(16)));
    for (int c = 0; c < 16; ++c) {
      float val = xp[(size_t)c * T_ + t];
      buf[c] = f2bf((val - mu) * rs * wl[c] + bl[c]);
    }
    unsigned short* dst = dbase + (size_t)t * 32;
    *(uint4*)dst       = *(uint4*)buf;
    *(uint4*)(dst + 8) = *(uint4*)(buf + 8);
  }
}

// ---------------------------------------------------------------------------
// QKV GEMM: async global_load_lds staging, ping-pong LDS, 1 barrier/iter.
// A = qwP panels [kp][1536][32], B = xnP panels [b][kp][1024][32].
// Epilogue scatters into q_t/k_t [bh][t][ch] and v_c [bh][ch][t].
// ---------------------------------------------------------------------------
__global__ __launch_bounds__(256) void gemm_qkv_kernel(
    const unsigned short* __restrict__ Wp, const unsigned short* __restrict__ xnP,
    const float* __restrict__ bias,
    unsigned short* __restrict__ q_t, unsigned short* __restrict__ k_t,
    unsigned short* __restrict__ v_c)
{
  int b = blockIdx.z;
  int m0 = blockIdx.y * 128, n0 = blockIdx.x * 128;
  int tid = threadIdx.x;
  int w = tid >> 6, lane = tid & 63, quad = lane >> 4, lr = lane & 15;
  int wm = w >> 1, wn = w & 1;

  __shared__ __align__(16) unsigned short As[2][128 * 32];
  __shared__ __align__(16) unsigned short Bs[2][128 * 32];

  f32x4_t acc[4][4];
  for (int i = 0; i < 4; ++i)
    for (int j = 0; j < 4; ++j) acc[i][j] = (f32x4_t){0.f, 0.f, 0.f, 0.f};

  const unsigned short* Abase = Wp + (size_t)m0 * 32;                 // + kp*1536*32
  const unsigned short* Bbase = xnP + ((size_t)(b * 16) * T_ + n0) * 32; // + kp*1024*32

  load_tile(Abase, As[0], tid);
  load_tile(Bbase, Bs[0], tid);

  for (int kp = 0; kp < 16; ++kp) {
    int cur = kp & 1;
    __syncthreads();                       // drains loads(kp); prior reads done
    if (kp < 15) {
      load_tile(Abase + (size_t)(kp + 1) * 1536 * 32, As[cur ^ 1], tid);
      load_tile(Bbase + (size_t)(kp + 1) * 1024 * 32, Bs[cur ^ 1], tid);
    }
    bf16x8_t af[4], bfv[4];
    for (int i = 0; i < 4; ++i)
      af[i]  = *(bf16x8_t*)&As[cur][(wm * 64 + i * 16 + lr) * 32 + quad * 8];
    for (int j = 0; j < 4; ++j)
      bfv[j] = *(bf16x8_t*)&Bs[cur][(wn * 64 + j * 16 + lr) * 32 + quad * 8];
    for (int i = 0; i < 4; ++i)
      for (int j = 0; j < 4; ++j)
        acc[i][j] = MFMA16(af[i], bfv[j], acc[i][j]);
  }

  for (int i = 0; i < 4; ++i) {
    int ob = m0 + wm * 64 + i * 16 + quad * 4;
    int h = ob / 192, r0 = ob % 192;
    for (int j = 0; j < 4; ++j) {
      int t = n0 + wn * 64 + j * 16 + lr;
      if (r0 < 128) {
        unsigned short pk[4] __attribute__((aligned(8)));
      #pragma unroll
        for (int r = 0; r < 4; ++r) pk[r] = f2bf(acc[i][j][r] + bias[ob + r]);
        unsigned short* base = (r0 < 64) ? q_t : k_t;
        int chn = (r0 < 64) ? r0 : r0 - 64;
        *(uint2*)&base[((size_t)(b * NH_ + h) * T_ + t) * CH_ + chn] = *(uint2*)pk;
      } else {
      #pragma unroll
        for (int r = 0; r < 4; ++r) {
          float vv = acc[i][j][r] + bias[ob + r];
          v_c[((size_t)(b * NH_ + h) * CH_ + (r0 - 128 + r)) * T_ + t] = f2bf(vv);
        }
      }
    }
  }
}

// ---------------------------------------------------------------------------
// Flash attention (unchanged R6 structure; epilogue writes panelized aP).
// Grid (64 bh, 16 t-tiles): XCD = bh%8 -> K/V L2-resident per head.
// ---------------------------------------------------------------------------
__global__ __launch_bounds__(256) void attn_kernel(
    const unsigned short* __restrict__ q_t, const unsigned short* __restrict__ k_t,
    const unsigned short* __restrict__ v_c, unsigned short* __restrict__ aP)
{
  int bh = blockIdx.x;
  int t0 = blockIdx.y * 64;
  int tid = threadIdx.x;
  int w = tid >> 6, lane = tid & 63, quad = lane >> 4, lr = lane & 15;

  __shared__ __align__(16) unsigned short q_s[64][72];
  __shared__ __align__(16) unsigned short k_s[64][72];
  __shared__ __align__(16) unsigned short v_s[64][72];
  __shared__ __align__(16) unsigned short p_s[64][72];

  int r0 = tid >> 3, c0 = (tid & 7) * 8;    // 64x64 tile: chunk0 rows 0..31
  *(uint4*)&q_s[r0][c0] =
      *(const uint4*)&q_t[((size_t)bh * T_ + t0 + r0) * CH_ + c0];
  *(uint4*)&q_s[r0 + 32][c0] =
      *(const uint4*)&q_t[((size_t)bh * T_ + t0 + r0 + 32) * CH_ + c0];

  uint4 kr0 = *(const uint4*)&k_t[((size_t)bh * T_ + r0) * CH_ + c0];
  uint4 kr1 = *(const uint4*)&k_t[((size_t)bh * T_ + r0 + 32) * CH_ + c0];
  uint4 vr0 = *(const uint4*)&v_c[((size_t)bh * CH_ + r0) * T_ + c0];
  uint4 vr1 = *(const uint4*)&v_c[((size_t)bh * CH_ + r0 + 32) * T_ + c0];

  __syncthreads();
  bf16x8_t aq[2];
  aq[0] = *(bf16x8_t*)&q_s[w * 16 + lr][quad * 8];
  aq[1] = *(bf16x8_t*)&q_s[w * 16 + lr][32 + quad * 8];

  bf16x8_t ones8;
  {
    short ov = (lr == 0) ? (short)0x3F80 : (short)0;
    for (int e = 0; e < 8; ++e) ones8[e] = ov;
  }

  f32x4_t o_acc[4], o_l;
  for (int j = 0; j < 4; ++j) o_acc[j] = (f32x4_t){0.f, 0.f, 0.f, 0.f};
  o_l = (f32x4_t){0.f, 0.f, 0.f, 0.f};

  const float SCL = 0.18033688f;   // 0.125 * log2(e)
  const float MSH = 11.541560f;    // 8 * log2(e)

  for (int s0 = 0; s0 < T_; s0 += 64) {
    __syncthreads();
    *(uint4*)&k_s[r0][c0]      = kr0;
    *(uint4*)&k_s[r0 + 32][c0] = kr1;
    *(uint4*)&v_s[r0][c0]      = vr0;
    *(uint4*)&v_s[r0 + 32][c0] = vr1;
    if (s0 + 64 < T_) {
      kr0 = *(const uint4*)&k_t[((size_t)bh * T_ + s0 + 64 + r0) * CH_ + c0];
      kr1 = *(const uint4*)&k_t[((size_t)bh * T_ + s0 + 96 + r0) * CH_ + c0];
      vr0 = *(const uint4*)&v_c[((size_t)bh * CH_ + r0) * T_ + s0 + 64 + c0];
      vr1 = *(const uint4*)&v_c[((size_t)bh * CH_ + r0 + 32) * T_ + s0 + 64 + c0];
    }
    __syncthreads();

    f32x4_t sc[4];
    for (int j = 0; j < 4; ++j) {
      f32x4_t a2 = (f32x4_t){0.f, 0.f, 0.f, 0.f};
      for (int kk = 0; kk < 2; ++kk) {
        bf16x8_t bk = *(bf16x8_t*)&k_s[j * 16 + lr][kk * 32 + quad * 8];
        a2 = MFMA16(aq[kk], bk, a2);
      }
      sc[j] = a2;
    }

    for (int j = 0; j < 4; ++j)
      for (int r = 0; r < 4; ++r) {
        float p = __builtin_amdgcn_exp2f(sc[j][r] * SCL - MSH);
        union { float f; unsigned u; } cv; cv.f = p;
        p_s[w * 16 + quad * 4 + r][j * 16 + lr] = (unsigned short)(cv.u >> 16);
      }
    bf16x8_t ap[2];
    ap[0] = *(bf16x8_t*)&p_s[w * 16 + lr][quad * 8];
    ap[1] = *(bf16x8_t*)&p_s[w * 16 + lr][32 + quad * 8];

    o_l = MFMA16(ap[0], ones8, o_l);
    o_l = MFMA16(ap[1], ones8, o_l);
    for (int j = 0; j < 4; ++j)
      for (int kk = 0; kk < 2; ++kk) {
        bf16x8_t bv = *(bf16x8_t*)&v_s[j * 16 + lr][kk * 32 + quad * 8];
        o_acc[j] = MFMA16(ap[kk], bv, o_acc[j]);
      }
  }

  float lv[4];
  for (int r = 0; r < 4; ++r) lv[r] = __shfl(o_l[r], lane & 48, 64);
  for (int r = 0; r < 4; ++r) {
    float inv = 1.f / lv[r];
    for (int j = 0; j < 4; ++j)
      q_s[w * 16 + quad * 4 + r][j * 16 + lr] = f2bf(o_acc[j][r] * inv);
  }
  __syncthreads();
  // panelized store: aP[b][kp = h*2 + (c0>=32)][t][32]
  {
    int b = bh >> 3, h = bh & 7;
    size_t pb = (size_t)(b * 16 + h * 2 + (c0 >= 32 ? 1 : 0)) * T_;
    int cc = c0 & 31;
    *(uint4*)&aP[(pb + t0 + r0) * 32 + cc]      = *(uint4*)&q_s[r0][c0];
    *(uint4*)&aP[(pb + t0 + r0 + 32) * 32 + cc] = *(uint4*)&q_s[r0 + 32][c0];
  }
}

// ---------------------------------------------------------------------------
// Proj GEMM: same async ping-pong structure. A = pwP [kp][512][32],
// B = aP [b][kp][1024][32]. Epilogue: bias + fp32 residual -> out [b][o][t].
// ---------------------------------------------------------------------------
__global__ __launch_bounds__(256) void gemm_proj_kernel(
    const unsigned short* __restrict__ Wp, const unsigned short* __restrict__ aP,
    const float* __restrict__ bias, const float* __restrict__ xres,
    float* __restrict__ out)
{
  int b = blockIdx.z;
  int m0 = blockIdx.y * 128, n0 = blockIdx.x * 128;
  int tid = threadIdx.x;
  int w = tid >> 6, lane = tid & 63, quad = lane >> 4, lr = lane & 15;
  int wm = w >> 1, wn = w & 1;

  __shared__ __align__(16) unsigned short As[2][128 * 32];
  __shared__ __align__(16) unsigned short Bs[2][128 * 32];

  f32x4_t acc[4][4];
  for (int i = 0; i < 4; ++i)
    for (int j = 0; j < 4; ++j) acc[i][j] = (f32x4_t){0.f, 0.f, 0.f, 0.f};

  const unsigned short* Abase = Wp + (size_t)m0 * 32;                  // + kp*512*32
  const unsigned short* Bbase = aP + ((size_t)(b * 16) * T_ + n0) * 32; // + kp*1024*32

  load_tile(Abase, As[0], tid);
  load_tile(Bbase, Bs[0], tid);

  for (int kp = 0; kp < 16; ++kp) {
    int cur = kp & 1;
    __syncthreads();
    if (kp < 15) {
      load_tile(Abase + (size_t)(kp + 1) * 512 * 32, As[cur ^ 1], tid);
      load_tile(Bbase + (size_t)(kp + 1) * 1024 * 32, Bs[cur ^ 1], tid);
    }
    bf16x8_t af[4], bfv[4];
    for (int i = 0; i < 4; ++i)
      af[i]  = *(bf16x8_t*)&As[cur][(wm * 64 + i * 16 + lr) * 32 + quad * 8];
    for (int j = 0; j < 4; ++j)
      bfv[j] = *(bf16x8_t*)&Bs[cur][(wn * 64 + j * 16 + lr) * 32 + quad * 8];
    for (int i = 0; i < 4; ++i)
      for (int j = 0; j < 4; ++j)
        acc[i][j] = MFMA16(af[i], bfv[j], acc[i][j]);
  }

  for (int i = 0; i < 4; ++i) {
    int ob = m0 + wm * 64 + i * 16 + quad * 4;
    for (int j = 0; j < 4; ++j) {
      int t = n0 + wn * 64 + j * 16 + lr;
    #pragma unroll
      for (int r = 0; r < 4; ++r) {
        size_t idx = ((size_t)(b * C_ + ob + r)) * T_ + t;
        out[idx] = acc[i][j][r] + bias[ob + r] + xres[idx];
      }
    }
  }
}

// ---------------------------------------------------------------------------
extern "C" void kernel_launch(void* const* d_in, const int* in_sizes, int n_in,
                              void* d_out, int out_size, void* d_ws, size_t ws_size,
                              hipStream_t stream)
{
  const float* x      = (const float*)d_in[0];
  const float* norm_w = (const float*)d_in[1];
  const float* norm_b = (const float*)d_in[2];
  const float* qkv_w  = (const float*)d_in[3];
  const float* qkv_b  = (const float*)d_in[4];
  const float* proj_w = (const float*)d_in[5];
  const float* proj_b = (const float*)d_in[6];
  float* out = (float*)d_out;

  char* ws = (char*)d_ws;
  unsigned short* qwP = (unsigned short*)ws;                       // 1.5 MiB
  unsigned short* pwP = (unsigned short*)(ws + 1572864);           // 0.5 MiB
  unsigned short* xnP = (unsigned short*)(ws + 2097152);           // 8 MiB
  unsigned short* q_t = (unsigned short*)(ws + 10485760);          // 8 MiB
  unsigned short* k_t = (unsigned short*)(ws + 18874368);          // 8 MiB
  unsigned short* v_c = (unsigned short*)(ws + 27262976);          // 8 MiB
  unsigned short* aP  = (unsigned short*)(ws + 35651584);          // 8 MiB

  prep_gn_kernel<<<dim3(256 + 1024), dim3(256), 0, stream>>>(
      x, norm_w, norm_b, xnP, qkv_w, proj_w, qwP, pwP);

  gemm_qkv_kernel<<<dim3(T_ / 128, 1536 / 128, B_), dim3(256), 0, stream>>>(
      qwP, xnP, qkv_b, q_t, k_t, v_c);

  attn_kernel<<<dim3(B_ * NH_, T_ / 64), dim3(256), 0, stream>>>(q_t, k_t, v_c, aP);

  gemm_proj_kernel<<<dim3(T_ / 128, C_ / 128, B_), dim3(256), 0, stream>>>(
      pwP, aP, proj_b, x, out);
}

// Round 8
// 164.453 us; speedup vs baseline: 1.0170x; 1.0170x over previous
//
#include <hip/hip_runtime.h>
#include <math.h>

typedef float f32x4_t __attribute__((ext_vector_type(4)));
typedef short bf16x8_t __attribute__((ext_vector_type(8)));

#define B_   8
#define C_   512
#define T_   1024
#define NH_  8
#define CH_  64
#define EPSF 1e-5f

#define MFMA16(a, b, c) __builtin_amdgcn_mfma_f32_16x16x32_bf16((a), (b), (c), 0, 0, 0)

__device__ __forceinline__ unsigned short f2bf(float f) {
  union { float f; unsigned u; } v; v.f = f;
  unsigned r = v.u + 0x7FFFu + ((v.u >> 16) & 1u);
  return (unsigned short)(r >> 16);
}

// async 16B/lane direct global->LDS (global_load_lds_dwordx4).
typedef const unsigned int u32_g __attribute__((address_space(1)));
typedef unsigned int u32_l __attribute__((address_space(3)));
__device__ __forceinline__ void gld16(const unsigned short* g, unsigned short* l) {
  __builtin_amdgcn_global_load_lds((u32_g*)g, (u32_l*)l, 16, 0, 0);
}
// stage one 128x32 bf16 tile (8KB, globally contiguous) with 256 threads
__device__ __forceinline__ void load_tile(const unsigned short* g,
                                          unsigned short* l, int tid) {
  int wb = (tid >> 6) * 512;          // wave-uniform lds chunk (1KB/wave)
  gld16(g + tid * 8,        l + wb);
  gld16(g + 2048 + tid * 8, l + 2048 + wb);
}

// ---------------------------------------------------------------------------
// Fused prep: blocks 0..255 GroupNorm (single-pass, x register-cached)
// -> xnP[b][kp][t][32] panels; blocks 256.. weight panels.
// ---------------------------------------------------------------------------
__global__ __launch_bounds__(256) void prep_gn_kernel(
    const float* __restrict__ x, const float* __restrict__ w,
    const float* __restrict__ bvec, unsigned short* __restrict__ xnP,
    const float* __restrict__ qw_f, const float* __restrict__ pw_f,
    unsigned short* __restrict__ qwP, unsigned short* __restrict__ pwP)
{
  int tid = threadIdx.x;
  if (blockIdx.x >= 256) {
    int idx = (blockIdx.x - 256) * 256 + tid;    // float4 granularity
    const int N1 = 1536 * 512 / 4;
    const int N2 = 512 * 512 / 4;
    if (idx < N1) {
      float4 v = ((const float4*)qw_f)[idx];
      int o = idx >> 7, cq = (idx & 127) * 4;
      uint2 ov;
      ov.x = (unsigned)f2bf(v.x) | ((unsigned)f2bf(v.y) << 16);
      ov.y = (unsigned)f2bf(v.z) | ((unsigned)f2bf(v.w) << 16);
      *(uint2*)&qwP[((size_t)(cq >> 5) * 1536 + o) * 32 + (cq & 31)] = ov;
    } else if (idx < N1 + N2) {
      int j = idx - N1;
      float4 v = ((const float4*)pw_f)[j];
      int o = j >> 7, cq = (j & 127) * 4;
      uint2 ov;
      ov.x = (unsigned)f2bf(v.x) | ((unsigned)f2bf(v.y) << 16);
      ov.y = (unsigned)f2bf(v.z) | ((unsigned)f2bf(v.w) << 16);
      *(uint2*)&pwP[((size_t)(cq >> 5) * 512 + o) * 32 + (cq & 31)] = ov;
    }
    return;
  }

  int blk = blockIdx.x;            // b*32 + g
  int b = blk >> 5, g = blk & 31;
  const float* xp = x + ((size_t)(b * C_ + g * 16)) * T_;

  // register-cache: thread owns t = 4*tid..4*tid+3 for all 16 channels
  float4 xr[16];
#pragma unroll
  for (int k = 0; k < 16; ++k)
    xr[k] = *(const float4*)(xp + (size_t)k * T_ + tid * 4);

  float s = 0.f, s2 = 0.f;
#pragma unroll
  for (int k = 0; k < 16; ++k) {
    float4 v = xr[k];
    s  += v.x + v.y + v.z + v.w;
    s2 += v.x * v.x + v.y * v.y + v.z * v.z + v.w * v.w;
  }
  for (int off = 32; off; off >>= 1) {
    s  += __shfl_down(s,  off, 64);
    s2 += __shfl_down(s2, off, 64);
  }
  __shared__ float rs_[4], r2_[4];
  __shared__ float mu_s, rsig_s;
  int wid = tid >> 6, lane = tid & 63;
  if (lane == 0) { rs_[wid] = s; r2_[wid] = s2; }
  __syncthreads();
  if (tid == 0) {
    float ts = rs_[0] + rs_[1] + rs_[2] + rs_[3];
    float t2 = r2_[0] + r2_[1] + r2_[2] + r2_[3];
    const float N = 16.f * 1024.f;
    float mu = ts / N;
    float var = t2 / N - mu * mu;
    mu_s = mu;
    rsig_s = rsqrtf(var + EPSF);
  }
  __syncthreads();
  float mu = mu_s, rs = rsig_s;

  float wl[16], bl[16];
#pragma unroll
  for (int c = 0; c < 16; ++c) { wl[c] = w[g * 16 + c]; bl[c] = bvec[g * 16 + c]; }

  // group g -> panel kp = g>>1, half offset (g&1)*16
  unsigned short* dbase = xnP + ((size_t)(b * 16 + (g >> 1)) * T_) * 32 + (g & 1) * 16;
#pragma unroll
  for (int j = 0; j < 4; ++j) {
    int t = tid * 4 + j;
    unsigned short buf[16] __attribute__((aligned(16)));
#pragma unroll
    for (int k = 0; k < 16; ++k) {
      float val = ((const float*)&xr[k])[j];
      buf[k] = f2bf((val - mu) * rs * wl[k] + bl[k]);
    }
    unsigned short* dst = dbase + (size_t)t * 32;
    *(uint4*)dst       = *(uint4*)buf;
    *(uint4*)(dst + 8) = *(uint4*)(buf + 8);
  }
}

// ---------------------------------------------------------------------------
// QKV GEMM: async global_load_lds staging, ping-pong LDS, 1 barrier/iter.
// A = qwP panels [kp][1536][32], B = xnP panels [b][kp][1024][32].
// Epilogue: q/k sections staged through LDS -> fully coalesced stores;
// v sections direct ([ch][t], 32B segments).
// ---------------------------------------------------------------------------
__global__ __launch_bounds__(256) void gemm_qkv_kernel(
    const unsigned short* __restrict__ Wp, const unsigned short* __restrict__ xnP,
    const float* __restrict__ bias,
    unsigned short* __restrict__ q_t, unsigned short* __restrict__ k_t,
    unsigned short* __restrict__ v_c)
{
  int b = blockIdx.z;
  int m0 = blockIdx.y * 128, n0 = blockIdx.x * 128;
  int tid = threadIdx.x;
  int w = tid >> 6, lane = tid & 63, quad = lane >> 4, lr = lane & 15;
  int wm = w >> 1, wn = w & 1;

  // union: GEMM ping-pong (32KB) / epilogue stage 2 x [128][68] (34.8KB)
  __shared__ __align__(16) unsigned short smem[17408];
  unsigned short* As0 = smem;
  unsigned short* As1 = smem + 4096;
  unsigned short* Bs0 = smem + 8192;
  unsigned short* Bs1 = smem + 12288;

  f32x4_t acc[4][4];
  for (int i = 0; i < 4; ++i)
    for (int j = 0; j < 4; ++j) acc[i][j] = (f32x4_t){0.f, 0.f, 0.f, 0.f};

  const unsigned short* Abase = Wp + (size_t)m0 * 32;                   // + kp*1536*32
  const unsigned short* Bbase = xnP + ((size_t)(b * 16) * T_ + n0) * 32; // + kp*1024*32

  load_tile(Abase, As0, tid);
  load_tile(Bbase, Bs0, tid);

  for (int kp = 0; kp < 16; ++kp) {
    unsigned short* Ac = (kp & 1) ? As1 : As0;
    unsigned short* Bc = (kp & 1) ? Bs1 : Bs0;
    __syncthreads();                       // drains loads(kp); prior reads done
    if (kp < 15) {
      load_tile(Abase + (size_t)(kp + 1) * 1536 * 32, (kp & 1) ? As0 : As1, tid);
      load_tile(Bbase + (size_t)(kp + 1) * 1024 * 32, (kp & 1) ? Bs0 : Bs1, tid);
    }
    bf16x8_t af[4], bfv[4];
    for (int i = 0; i < 4; ++i)
      af[i]  = *(bf16x8_t*)&Ac[(wm * 64 + i * 16 + lr) * 32 + quad * 8];
    for (int j = 0; j < 4; ++j)
      bfv[j] = *(bf16x8_t*)&Bc[(wn * 64 + j * 16 + lr) * 32 + quad * 8];
    for (int i = 0; i < 4; ++i)
      for (int j = 0; j < 4; ++j)
        acc[i][j] = MFMA16(af[i], bfv[j], acc[i][j]);
  }

  __syncthreads();                 // all GEMM LDS reads done; smem reusable

  // ---- epilogue ----
  int secbase = m0 + wm * 64;      // this wave-pair's 64-row section
  int h = secbase / 192, r0 = secbase % 192;

  if (r0 == 128) {
    // v section: direct [bh][ch][t] stores (t across lanes -> merged)
    for (int i = 0; i < 4; ++i) {
      int ob = secbase + i * 16 + quad * 4;
      for (int j = 0; j < 4; ++j) {
        int t = n0 + wn * 64 + j * 16 + lr;
      #pragma unroll
        for (int r = 0; r < 4; ++r) {
          float vv = acc[i][j][r] + bias[ob + r];
          v_c[((size_t)(b * NH_ + h) * CH_ + (ob - secbase + r)) * T_ + t] = f2bf(vv);
        }
      }
    }
  } else {
    // q/k section: stage [t][o] (pad 68) in LDS
    unsigned short* st = smem + wm * (128 * 68);
    for (int i = 0; i < 4; ++i) {
      int ol = i * 16 + quad * 4;
      for (int j = 0; j < 4; ++j) {
        int tl = wn * 64 + j * 16 + lr;
        unsigned short pk[4] __attribute__((aligned(8)));
      #pragma unroll
        for (int r = 0; r < 4; ++r) pk[r] = f2bf(acc[i][j][r] + bias[secbase + ol + r]);
        *(uint2*)&st[tl * 68 + ol] = *(uint2*)pk;
      }
    }
  }
  __syncthreads();

  // coalesced readout of staged q/k sections
  for (int sec = 0; sec < 2; ++sec) {
    int sb = m0 + sec * 64;
    int hh = sb / 192, rr = sb % 192;
    if (rr == 128) continue;
    unsigned short* dst = ((rr == 0) ? q_t : k_t) +
                          ((size_t)(b * NH_ + hh) * T_ + n0) * CH_;
    const unsigned short* st = smem + sec * (128 * 68);
    for (int u = 0; u < 4; ++u) {
      int idx = u * 256 + tid;     // 1024 chunks: 128 t x 8 chunks
      int tl = idx >> 3, c8 = (idx & 7) * 8;
      *(uint4*)&dst[(size_t)tl * CH_ + c8] = *(const uint4*)&st[tl * 68 + c8];
    }
  }
}

// ---------------------------------------------------------------------------
// Flash attention (R6 structure; epilogue writes panelized aP).
// Grid (64 bh, 16 t-tiles): XCD = bh%8 -> K/V L2-resident per head.
// ---------------------------------------------------------------------------
__global__ __launch_bounds__(256) void attn_kernel(
    const unsigned short* __restrict__ q_t, const unsigned short* __restrict__ k_t,
    const unsigned short* __restrict__ v_c, unsigned short* __restrict__ aP)
{
  int bh = blockIdx.x;
  int t0 = blockIdx.y * 64;
  int tid = threadIdx.x;
  int w = tid >> 6, lane = tid & 63, quad = lane >> 4, lr = lane & 15;

  __shared__ __align__(16) unsigned short q_s[64][72];
  __shared__ __align__(16) unsigned short k_s[64][72];
  __shared__ __align__(16) unsigned short v_s[64][72];
  __shared__ __align__(16) unsigned short p_s[64][72];

  int r0 = tid >> 3, c0 = (tid & 7) * 8;    // 64x64 tile: chunk0 rows 0..31
  *(uint4*)&q_s[r0][c0] =
      *(const uint4*)&q_t[((size_t)bh * T_ + t0 + r0) * CH_ + c0];
  *(uint4*)&q_s[r0 + 32][c0] =
      *(const uint4*)&q_t[((size_t)bh * T_ + t0 + r0 + 32) * CH_ + c0];

  uint4 kr0 = *(const uint4*)&k_t[((size_t)bh * T_ + r0) * CH_ + c0];
  uint4 kr1 = *(const uint4*)&k_t[((size_t)bh * T_ + r0 + 32) * CH_ + c0];
  uint4 vr0 = *(const uint4*)&v_c[((size_t)bh * CH_ + r0) * T_ + c0];
  uint4 vr1 = *(const uint4*)&v_c[((size_t)bh * CH_ + r0 + 32) * T_ + c0];

  __syncthreads();
  bf16x8_t aq[2];
  aq[0] = *(bf16x8_t*)&q_s[w * 16 + lr][quad * 8];
  aq[1] = *(bf16x8_t*)&q_s[w * 16 + lr][32 + quad * 8];

  bf16x8_t ones8;
  {
    short ov = (lr == 0) ? (short)0x3F80 : (short)0;
    for (int e = 0; e < 8; ++e) ones8[e] = ov;
  }

  f32x4_t o_acc[4], o_l;
  for (int j = 0; j < 4; ++j) o_acc[j] = (f32x4_t){0.f, 0.f, 0.f, 0.f};
  o_l = (f32x4_t){0.f, 0.f, 0.f, 0.f};

  const float SCL = 0.18033688f;   // 0.125 * log2(e)
  const float MSH = 11.541560f;    // 8 * log2(e)

  for (int s0 = 0; s0 < T_; s0 += 64) {
    __syncthreads();
    *(uint4*)&k_s[r0][c0]      = kr0;
    *(uint4*)&k_s[r0 + 32][c0] = kr1;
    *(uint4*)&v_s[r0][c0]      = vr0;
    *(uint4*)&v_s[r0 + 32][c0] = vr1;
    if (s0 + 64 < T_) {
      kr0 = *(const uint4*)&k_t[((size_t)bh * T_ + s0 + 64 + r0) * CH_ + c0];
      kr1 = *(const uint4*)&k_t[((size_t)bh * T_ + s0 + 96 + r0) * CH_ + c0];
      vr0 = *(const uint4*)&v_c[((size_t)bh * CH_ + r0) * T_ + s0 + 64 + c0];
      vr1 = *(const uint4*)&v_c[((size_t)bh * CH_ + r0 + 32) * T_ + s0 + 64 + c0];
    }
    __syncthreads();

    f32x4_t sc[4];
    for (int j = 0; j < 4; ++j) {
      f32x4_t a2 = (f32x4_t){0.f, 0.f, 0.f, 0.f};
      for (int kk = 0; kk < 2; ++kk) {
        bf16x8_t bk = *(bf16x8_t*)&k_s[j * 16 + lr][kk * 32 + quad * 8];
        a2 = MFMA16(aq[kk], bk, a2);
      }
      sc[j] = a2;
    }

    for (int j = 0; j < 4; ++j)
      for (int r = 0; r < 4; ++r) {
        float p = __builtin_amdgcn_exp2f(sc[j][r] * SCL - MSH);
        union { float f; unsigned u; } cv; cv.f = p;
        p_s[w * 16 + quad * 4 + r][j * 16 + lr] = (unsigned short)(cv.u >> 16);
      }
    bf16x8_t ap[2];
    ap[0] = *(bf16x8_t*)&p_s[w * 16 + lr][quad * 8];
    ap[1] = *(bf16x8_t*)&p_s[w * 16 + lr][32 + quad * 8];

    o_l = MFMA16(ap[0], ones8, o_l);
    o_l = MFMA16(ap[1], ones8, o_l);
    for (int j = 0; j < 4; ++j)
      for (int kk = 0; kk < 2; ++kk) {
        bf16x8_t bv = *(bf16x8_t*)&v_s[j * 16 + lr][kk * 32 + quad * 8];
        o_acc[j] = MFMA16(ap[kk], bv, o_acc[j]);
      }
  }

  float lv[4];
  for (int r = 0; r < 4; ++r) lv[r] = __shfl(o_l[r], lane & 48, 64);
  for (int r = 0; r < 4; ++r) {
    float inv = 1.f / lv[r];
    for (int j = 0; j < 4; ++j)
      q_s[w * 16 + quad * 4 + r][j * 16 + lr] = f2bf(o_acc[j][r] * inv);
  }
  __syncthreads();
  // panelized store: aP[b][kp = h*2 + (c0>=32)][t][32]
  {
    int b = bh >> 3, h = bh & 7;
    size_t pb = (size_t)(b * 16 + h * 2 + (c0 >= 32 ? 1 : 0)) * T_;
    int cc = c0 & 31;
    *(uint4*)&aP[(pb + t0 + r0) * 32 + cc]      = *(uint4*)&q_s[r0][c0];
    *(uint4*)&aP[(pb + t0 + r0 + 32) * 32 + cc] = *(uint4*)&q_s[r0 + 32][c0];
  }
}

// ---------------------------------------------------------------------------
// Proj GEMM: async ping-pong. A = pwP [kp][512][32], B = aP [b][kp][1024][32].
// Epilogue: bias + fp32 residual -> out [b][o][t].
// ---------------------------------------------------------------------------
__global__ __launch_bounds__(256) void gemm_proj_kernel(
    const unsigned short* __restrict__ Wp, const unsigned short* __restrict__ aP,
    const float* __restrict__ bias, const float* __restrict__ xres,
    float* __restrict__ out)
{
  int b = blockIdx.z;
  int m0 = blockIdx.y * 128, n0 = blockIdx.x * 128;
  int tid = threadIdx.x;
  int w = tid >> 6, lane = tid & 63, quad = lane >> 4, lr = lane & 15;
  int wm = w >> 1, wn = w & 1;

  __shared__ __align__(16) unsigned short As[2][128 * 32];
  __shared__ __align__(16) unsigned short Bs[2][128 * 32];

  f32x4_t acc[4][4];
  for (int i = 0; i < 4; ++i)
    for (int j = 0; j < 4; ++j) acc[i][j] = (f32x4_t){0.f, 0.f, 0.f, 0.f};

  const unsigned short* Abase = Wp + (size_t)m0 * 32;                  // + kp*512*32
  const unsigned short* Bbase = aP + ((size_t)(b * 16) * T_ + n0) * 32; // + kp*1024*32

  load_tile(Abase, As[0], tid);
  load_tile(Bbase, Bs[0], tid);

  for (int kp = 0; kp < 16; ++kp) {
    int cur = kp & 1;
    __syncthreads();
    if (kp < 15) {
      load_tile(Abase + (size_t)(kp + 1) * 512 * 32, As[cur ^ 1], tid);
      load_tile(Bbase + (size_t)(kp + 1) * 1024 * 32, Bs[cur ^ 1], tid);
    }
    bf16x8_t af[4], bfv[4];
    for (int i = 0; i < 4; ++i)
      af[i]  = *(bf16x8_t*)&As[cur][(wm * 64 + i * 16 + lr) * 32 + quad * 8];
    for (int j = 0; j < 4; ++j)
      bfv[j] = *(bf16x8_t*)&Bs[cur][(wn * 64 + j * 16 + lr) * 32 + quad * 8];
    for (int i = 0; i < 4; ++i)
      for (int j = 0; j < 4; ++j)
        acc[i][j] = MFMA16(af[i], bfv[j], acc[i][j]);
  }

  for (int i = 0; i < 4; ++i) {
    int ob = m0 + wm * 64 + i * 16 + quad * 4;
    for (int j = 0; j < 4; ++j) {
      int t = n0 + wn * 64 + j * 16 + lr;
    #pragma unroll
      for (int r = 0; r < 4; ++r) {
        size_t idx = ((size_t)(b * C_ + ob + r)) * T_ + t;
        out[idx] = acc[i][j][r] + bias[ob + r] + xres[idx];
      }
    }
  }
}

// ---------------------------------------------------------------------------
extern "C" void kernel_launch(void* const* d_in, const int* in_sizes, int n_in,
                              void* d_out, int out_size, void* d_ws, size_t ws_size,
                              hipStream_t stream)
{
  const float* x      = (const float*)d_in[0];
  const float* norm_w = (const float*)d_in[1];
  const float* norm_b = (const float*)d_in[2];
  const float* qkv_w  = (const float*)d_in[3];
  const float* qkv_b  = (const float*)d_in[4];
  const float* proj_w = (const float*)d_in[5];
  const float* proj_b = (const float*)d_in[6];
  float* out = (float*)d_out;

  char* ws = (char*)d_ws;
  unsigned short* qwP = (unsigned short*)ws;                       // 1.5 MiB
  unsigned short* pwP = (unsigned short*)(ws + 1572864);           // 0.5 MiB
  unsigned short* xnP = (unsigned short*)(ws + 2097152);           // 8 MiB
  unsigned short* q_t = (unsigned short*)(ws + 10485760);          // 8 MiB
  unsigned short* k_t = (unsigned short*)(ws + 18874368);          // 8 MiB
  unsigned short* v_c = (unsigned short*)(ws + 27262976);          // 8 MiB
  unsigned short* aP  = (unsigned short*)(ws + 35651584);          // 8 MiB

  prep_gn_kernel<<<dim3(256 + 1024), dim3(256), 0, stream>>>(
      x, norm_w, norm_b, xnP, qkv_w, proj_w, qwP, pwP);

  gemm_qkv_kernel<<<dim3(T_ / 128, 1536 / 128, B_), dim3(256), 0, stream>>>(
      qwP, xnP, qkv_b, q_t, k_t, v_c);

  attn_kernel<<<dim3(B_ * NH_, T_ / 64), dim3(256), 0, stream>>>(q_t, k_t, v_c, aP);

  gemm_proj_kernel<<<dim3(T_ / 128, C_ / 128, B_), dim3(256), 0, stream>>>(
      pwP, aP, proj_b, x, out);
}